// Round 16
// baseline (52.923 us; speedup 1.0000x reference)
//
#include <hip/hip_runtime.h>

#define D 64
#define CHARSET 128
#define GAMMA 1.0f
#define SPW 16          // segments per chunk
#define HPW 132         // padded hist row length (u32 words)
#define HWORDS (SPW * HPW)

typedef short  s8v  __attribute__((ext_vector_type(8)));   // bf16x8 (4 VGPR)
typedef float  f4v  __attribute__((ext_vector_type(4)));   // fp32x4 accum
typedef unsigned short u8s __attribute__((ext_vector_type(8)));
typedef unsigned short u4s __attribute__((ext_vector_type(4)));

__device__ __forceinline__ short f32_to_bf16(float f) {
    unsigned u = __builtin_bit_cast(unsigned, f);
    unsigned r = (u + 0x7FFFu + ((u >> 16) & 1u)) >> 16;   // RNE
    return (short)r;
}

// pack bf16(a)|bf16(b)<<16 for small ints (exact for ints < 256)
__device__ __forceinline__ int pack2(unsigned ca, unsigned cb) {
    unsigned fa = __builtin_bit_cast(unsigned, (float)ca);
    unsigned fb = __builtin_bit_cast(unsigned, (float)cb);
    return (int)__builtin_amdgcn_perm(fb, fa, 0x07060302u);
}

// Fused preproc: packed[c] = (seg[c]&15)*132 + char[c], segstart, bf16 tabT.
__global__ void preproc(const int* __restrict__ seg, const int* __restrict__ chr,
                        const float* __restrict__ emb,
                        int total, int n_seg_pad,
                        int* __restrict__ segstart,
                        unsigned short* __restrict__ packed,
                        unsigned short* __restrict__ tabT) {
    int q = blockIdx.x * blockDim.x + threadIdx.x;
    if (q < D * CHARSET) {
        int d = q >> 7, k = q & 127;
        tabT[q] = (unsigned short)f32_to_bf16(emb[k * D + d]);
    }
    int c0 = q * 4;
    if (c0 >= total) return;
    int v[4], ch[4];
    if (c0 + 3 < total) {
        int4 w = *(const int4*)&seg[c0]; v[0]=w.x; v[1]=w.y; v[2]=w.z; v[3]=w.w;
        int4 x = *(const int4*)&chr[c0]; ch[0]=x.x; ch[1]=x.y; ch[2]=x.z; ch[3]=x.w;
    } else {
        for (int i = 0; i < 4; ++i) {
            v[i]  = (c0 + i < total) ? seg[c0 + i] : 0;
            ch[i] = (c0 + i < total) ? chr[c0 + i] : 0;
        }
    }
    u4s pk;
    #pragma unroll
    for (int i = 0; i < 4; ++i)
        pk[i] = (unsigned short)((v[i] & (SPW - 1)) * HPW + ch[i]);
    if (c0 + 3 < total) *(u4s*)&packed[c0] = pk;
    else for (int i = 0; i < 4 && c0 + i < total; ++i) packed[c0 + i] = pk[i];

    int prev = (c0 == 0) ? -1 : seg[c0 - 1];
    int lim = min(4, total - c0);
    for (int i = 0; i < lim; ++i) {
        int cur = v[i];
        for (int s = prev + 1; s <= cur; ++s) segstart[s] = c0 + i;
        if (c0 + i == total - 1)
            for (int s = cur + 1; s <= n_seg_pad; ++s) segstart[s] = total;
        prev = cur;
    }
}

__global__ void reduce_partials(const float* __restrict__ p, int n,
                                float* __restrict__ out, float base) {
    __shared__ float red[16];
    float acc = 0.f;
    int nt4 = n >> 2;
    const float4* p4 = (const float4*)p;
    for (int i = threadIdx.x; i < nt4; i += 1024) { float4 v = p4[i]; acc += v.x + v.y + v.z + v.w; }
    for (int i = (nt4 << 2) + threadIdx.x; i < n; i += 1024) acc += p[i];
    #pragma unroll
    for (int off = 32; off > 0; off >>= 1) acc += __shfl_down(acc, off, 64);
    int wid = threadIdx.x >> 6, lane = threadIdx.x & 63;
    if (lane == 0) red[wid] = acc;
    __syncthreads();
    if (threadIdx.x == 0) { float s = base; for (int i = 0; i < 16; ++i) s += red[i]; out[0] = s; }
}

__global__ void init_out(float* out, float v) {
    if (threadIdx.x == 0 && blockIdx.x == 0) out[0] = v;
}

__device__ __forceinline__ int lower_bound64(const int* __restrict__ seg,
                                             int lo, int hi, int target, int lane) {
    while (hi - lo > 64) {
        int step = (hi - lo) >> 6;
        int idx = lo + lane * step;
        int v = seg[idx];
        unsigned long long mask = __ballot(v < target);
        if (mask == 0ull) { hi = lo; break; }
        int k = 63 - __clzll(mask);
        int nhi = (k == 63) ? hi : (lo + (k + 1) * step);
        lo = lo + k * step; hi = nhi;
    }
    if (hi > lo) {
        int idx = lo + lane;
        int v = (idx < hi) ? seg[idx] : 0x7FFFFFFF;
        lo += __popcll(__ballot(v < target));
    }
    return lo;
}

// ---------------- persistent pipelined main kernel ----------------
#define DECL_STATE(S) \
    int hid_##S[4], rid_##S[4], cbg_##S = 0, ce_##S = 0, wb_##S = 0; \
    bool val_##S = false; u8s sl0_##S; u4s sl1_##S; float hv_##S[16];

#define ISSUE_A(S, c) do { \
    val_##S = (c) < nchunks; \
    if (val_##S) { \
        int s0_ = (c) * SPW; \
        cbg_##S = segstart[s0_]; ce_##S = segstart[s0_ + SPW]; \
        wb_##S = cbg_##S & ~7; \
        _Pragma("unroll") \
        for (int j_ = 0; j_ < 4; ++j_) { \
            int s_ = s0_ + g4 * 4 + j_; bool v_ = s_ < n_triples; \
            hid_##S[j_] = v_ ? head_ids[s_] : 0; \
            rid_##S[j_] = v_ ? rel_ids[s_] : 0; } \
        sl0_##S = *(const u8s*)&packed[min(wb_##S + lane * 8, total_chars - 8)]; \
        sl1_##S = *(const u4s*)&packed[min(wb_##S + 512 + lane * 4, total_chars - 4)]; \
    } } while (0)

#define ISSUE_B(S) do { if (val_##S) { \
    _Pragma("unroll") \
    for (int r_ = 0; r_ < 4; ++r_) \
        _Pragma("unroll") \
        for (int ct_ = 0; ct_ < 4; ++ct_) \
            hv_##S[r_ * 4 + ct_] = ent_emb[(size_t)hid_##S[r_] * D + ct_ * 16 + col]; \
    } } while (0)

#define COMPUTE(S, T, c) do { if (val_##S) { \
    _Pragma("unroll") \
    for (int i_ = 0; i_ < 9; ++i_) { \
        int idx_ = i_ * 64 + lane; \
        if (idx_ < HWORDS / 4) ((uint4*)hq)[idx_] = make_uint4(0u,0u,0u,0u); } \
    _Pragma("unroll") \
    for (int e_ = 0; e_ < 8; ++e_) { \
        int c_ = wb_##S + lane * 8 + e_; \
        if (c_ >= cbg_##S && c_ < ce_##S) atomicAdd(&hq[sl0_##S[e_]], 1u); } \
    _Pragma("unroll") \
    for (int e_ = 0; e_ < 4; ++e_) { \
        int c_ = wb_##S + 512 + lane * 4 + e_; \
        if (c_ >= cbg_##S && c_ < ce_##S) atomicAdd(&hq[sl1_##S[e_]], 1u); } \
    for (int c_ = wb_##S + 768 + lane; c_ < ce_##S; c_ += 64) \
        atomicAdd(&hq[packed[c_]], 1u); \
    ISSUE_B(T); \
    f4v acc[4] = {(f4v)0.f, (f4v)0.f, (f4v)0.f, (f4v)0.f}; \
    _Pragma("unroll") \
    for (int st_ = 0; st_ < 4; ++st_) { \
        const unsigned* hr_ = &hq[col * HPW + st_ * 32 + g4 * 8]; \
        uint4 c0_ = *(const uint4*)hr_; \
        uint4 c1_ = *(const uint4*)(hr_ + 4); \
        int4 aw_; \
        aw_.x = pack2(c0_.x, c0_.y); aw_.y = pack2(c0_.z, c0_.w); \
        aw_.z = pack2(c1_.x, c1_.y); aw_.w = pack2(c1_.z, c1_.w); \
        s8v af_ = __builtin_bit_cast(s8v, aw_); \
        _Pragma("unroll") \
        for (int ct_ = 0; ct_ < 4; ++ct_) { \
            s8v bf_ = *(const s8v*)&tabT[(size_t)(ct_ * 16 + col) * CHARSET + st_ * 32 + g4 * 8]; \
            acc[ct_] = __builtin_amdgcn_mfma_f32_16x16x32_bf16(af_, bf_, acc[ct_], 0, 0, 0); } } \
    _Pragma("unroll") \
    for (int r_ = 0; r_ < 4; ++r_) { \
        int s_ = (c) * SPW + g4 * 4 + r_; \
        if (s_ < n_triples) { \
            const float* rp_ = &rel_emb[rid_##S[r_] * D]; \
            _Pragma("unroll") \
            for (int ct_ = 0; ct_ < 4; ++ct_) \
                wsum += fabsf(hv_##S[r_ * 4 + ct_] + rp_[ct_ * 16 + col] - acc[ct_][r_]); } } \
    } } while (0)

__global__ __launch_bounds__(64, 4) void attr_persist(
    const int* __restrict__ head_ids,
    const int* __restrict__ rel_ids,
    const float* __restrict__ rel_emb,
    const float* __restrict__ ent_emb,
    const unsigned short* __restrict__ tabT,
    const int* __restrict__ segstart,
    const unsigned short* __restrict__ packed,
    float* __restrict__ partials,
    int n_triples, int total_chars, int nchunks)
{
    __shared__ __align__(16) unsigned hq[HWORDS];     // 8.25 KB only

    const int lane = threadIdx.x;
    const int col = lane & 15, g4 = lane >> 4;
    const int NB = gridDim.x;

    DECL_STATE(A); DECL_STATE(B);
    float wsum = 0.f;

    int c = blockIdx.x;
    ISSUE_A(A, c);
    ISSUE_B(A);                       // one-time stall on ids
    while (c < nchunks) {
        ISSUE_A(B, c + NB);
        COMPUTE(A, B, c);             // hides B's load latency
        ISSUE_A(A, c + 2 * NB);
        COMPUTE(B, A, c + NB);        // hides A's load latency
        c += 2 * NB;
    }

    #pragma unroll
    for (int off = 32; off > 0; off >>= 1)
        wsum += __shfl_down(wsum, off, 64);
    if (lane == 0) partials[blockIdx.x] = wsum;
}

// ---------------- fallback (ws too small) ----------------
__global__ __launch_bounds__(64, 4) void attr_fallback(
    const int* __restrict__ char_ids,
    const int* __restrict__ seg_ids,
    const int* __restrict__ head_ids,
    const int* __restrict__ rel_ids,
    const float* __restrict__ char_emb,
    const float* __restrict__ rel_emb,
    const float* __restrict__ ent_emb,
    float* __restrict__ out,
    int n_triples, int total_chars, int nwaves)
{
    __shared__ __align__(16) unsigned hq[HWORDS];
    const int lane  = threadIdx.x;
    const int gwave = blockIdx.x;
    if (gwave >= nwaves) return;
    const int s0  = gwave * SPW;
    const int col = lane & 15, g4 = lane >> 4;

    int hid[4], rid[4];
    #pragma unroll
    for (int j = 0; j < 4; ++j) {
        int s = s0 + g4 * 4 + j;
        bool v = s < n_triples;
        hid[j] = v ? head_ids[s] : 0;
        rid[j] = v ? rel_ids[s]  : 0;
    }
    for (int i = lane; i < HWORDS / 4; i += 64)
        ((uint4*)hq)[i] = make_uint4(0u, 0u, 0u, 0u);
    int cb = lower_bound64(seg_ids, 0, total_chars, s0, lane);
    int ce = lower_bound64(seg_ids, cb, total_chars,
                           min(s0 + SPW, n_triples), lane);
    for (int c = cb + lane; c < ce; c += 64) {
        int sa = seg_ids[c], da = char_ids[c];
        atomicAdd(&hq[(sa - s0) * HPW + da], 1u);
    }
    float hv[16];
    #pragma unroll
    for (int r = 0; r < 4; ++r)
        #pragma unroll
        for (int ct = 0; ct < 4; ++ct)
            hv[r * 4 + ct] = ent_emb[(size_t)hid[r] * D + ct * 16 + col];

    f4v acc[4] = {(f4v)0.f, (f4v)0.f, (f4v)0.f, (f4v)0.f};
    #pragma unroll
    for (int st = 0; st < 4; ++st) {
        const unsigned* hr = &hq[col * HPW + st * 32 + g4 * 8];
        uint4 c0 = *(const uint4*)hr;
        uint4 c1 = *(const uint4*)(hr + 4);
        int4 aw;
        aw.x = pack2(c0.x, c0.y); aw.y = pack2(c0.z, c0.w);
        aw.z = pack2(c1.x, c1.y); aw.w = pack2(c1.z, c1.w);
        s8v af = __builtin_bit_cast(s8v, aw);
        #pragma unroll
        for (int ct = 0; ct < 4; ++ct) {
            s8v bfrag;
            #pragma unroll
            for (int e = 0; e < 8; ++e)
                bfrag[e] = f32_to_bf16(char_emb[(st * 32 + g4 * 8 + e) * D + ct * 16 + col]);
            acc[ct] = __builtin_amdgcn_mfma_f32_16x16x32_bf16(af, bfrag, acc[ct], 0, 0, 0);
        }
    }
    float part = 0.f;
    #pragma unroll
    for (int r = 0; r < 4; ++r) {
        int s = s0 + g4 * 4 + r;
        if (s < n_triples) {
            const float* rp = &rel_emb[rid[r] * D];
            #pragma unroll
            for (int ct = 0; ct < 4; ++ct)
                part += fabsf(hv[r * 4 + ct] + rp[ct * 16 + col] - acc[ct][r]);
        }
    }
    #pragma unroll
    for (int off = 32; off > 0; off >>= 1)
        part += __shfl_down(part, off, 64);
    if (lane == 0) atomicAdd(out, part);
}

extern "C" void kernel_launch(void* const* d_in, const int* in_sizes, int n_in,
                              void* d_out, int out_size, void* d_ws, size_t ws_size,
                              hipStream_t stream) {
    const int*   char_ids = (const int*)  d_in[0];
    const int*   seg_ids  = (const int*)  d_in[1];
    const int*   head_ids = (const int*)  d_in[2];
    const int*   rel_ids  = (const int*)  d_in[3];
    const float* char_emb = (const float*)d_in[4];
    const float* rel_emb  = (const float*)d_in[5];
    const float* ent_emb  = (const float*)d_in[6];
    float* out = (float*)d_out;

    const int total_chars = in_sizes[0];
    const int n_triples   = in_sizes[2];
    const int nchunks   = (n_triples + SPW - 1) / SPW;
    const int n_seg_pad = nchunks * SPW;
    const float base = (float)n_triples * GAMMA;
    const int nblk = min(4096, nchunks);      // 16 blocks/CU (LDS 8.25 KB, VGPR<=128)

    // ws: tabT bf16[8192] | segstart int[n_seg_pad+1] | partials float[nblk]
    //     | packed ushort[total_chars] (16B-aligned)
    unsigned short* tabT = (unsigned short*)d_ws;
    int*   segstart = (int*)((char*)d_ws + D * CHARSET * sizeof(unsigned short));
    float* partials = (float*)(segstart + n_seg_pad + 1);
    size_t off = ((size_t)((char*)(partials + nblk) - (char*)d_ws) + 15) & ~(size_t)15;
    unsigned short* packed = (unsigned short*)((char*)d_ws + off);
    const size_t need = off + (size_t)total_chars * sizeof(unsigned short);

    if (ws_size >= need) {
        const int pthreads = (total_chars + 3) / 4;
        preproc<<<(pthreads + 255) / 256, 256, 0, stream>>>(
            seg_ids, char_ids, char_emb, total_chars, n_seg_pad,
            segstart, packed, tabT);
        attr_persist<<<nblk, 64, 0, stream>>>(
            head_ids, rel_ids, rel_emb, ent_emb, tabT, segstart, packed,
            partials, n_triples, total_chars, nchunks);
        reduce_partials<<<1, 1024, 0, stream>>>(partials, nblk, out, base);
    } else {
        init_out<<<1, 64, 0, stream>>>(out, base);
        attr_fallback<<<nchunks, 64, 0, stream>>>(
            char_ids, seg_ids, head_ids, rel_ids,
            char_emb, rel_emb, ent_emb, out,
            n_triples, total_chars, nchunks);
    }
}

// Round 17
// 37.517 us; speedup vs baseline: 1.4106x; 1.4106x over previous
//
#include <hip/hip_runtime.h>

#define D 64
#define CHARSET 128
#define GAMMA 1.0f
#define SPW 16          // segments per chunk
#define HPW 132         // padded hist row length (u32 words)
#define HWORDS (SPW * HPW)

typedef short  s8v  __attribute__((ext_vector_type(8)));   // bf16x8 (4 VGPR)
typedef float  f4v  __attribute__((ext_vector_type(4)));   // fp32x4 accum
typedef unsigned short u8s __attribute__((ext_vector_type(8)));
typedef unsigned short u4s __attribute__((ext_vector_type(4)));

__device__ __forceinline__ short f32_to_bf16(float f) {
    unsigned u = __builtin_bit_cast(unsigned, f);
    unsigned r = (u + 0x7FFFu + ((u >> 16) & 1u)) >> 16;   // RNE
    return (short)r;
}

// pack bf16(a)|bf16(b)<<16 for small ints (exact for ints < 256)
__device__ __forceinline__ int pack2(unsigned ca, unsigned cb) {
    unsigned fa = __builtin_bit_cast(unsigned, (float)ca);
    unsigned fb = __builtin_bit_cast(unsigned, (float)cb);
    return (int)__builtin_amdgcn_perm(fb, fa, 0x07060302u);
}

// Fused preproc: packed[c] = (seg[c]&15)*132 + char[c], segstart, bf16 tabT.
__global__ void preproc(const int* __restrict__ seg, const int* __restrict__ chr,
                        const float* __restrict__ emb,
                        int total, int n_seg_pad,
                        int* __restrict__ segstart,
                        unsigned short* __restrict__ packed,
                        unsigned short* __restrict__ tabT) {
    int q = blockIdx.x * blockDim.x + threadIdx.x;
    if (q < D * CHARSET) {
        int d = q >> 7, k = q & 127;
        tabT[q] = (unsigned short)f32_to_bf16(emb[k * D + d]);
    }
    int c0 = q * 4;
    if (c0 >= total) return;
    int v[4], ch[4];
    if (c0 + 3 < total) {
        int4 w = *(const int4*)&seg[c0]; v[0]=w.x; v[1]=w.y; v[2]=w.z; v[3]=w.w;
        int4 x = *(const int4*)&chr[c0]; ch[0]=x.x; ch[1]=x.y; ch[2]=x.z; ch[3]=x.w;
    } else {
        for (int i = 0; i < 4; ++i) {
            v[i]  = (c0 + i < total) ? seg[c0 + i] : 0;
            ch[i] = (c0 + i < total) ? chr[c0 + i] : 0;
        }
    }
    u4s pk;
    #pragma unroll
    for (int i = 0; i < 4; ++i)
        pk[i] = (unsigned short)((v[i] & (SPW - 1)) * HPW + ch[i]);
    if (c0 + 3 < total) *(u4s*)&packed[c0] = pk;
    else for (int i = 0; i < 4 && c0 + i < total; ++i) packed[c0 + i] = pk[i];

    int prev = (c0 == 0) ? -1 : seg[c0 - 1];
    int lim = min(4, total - c0);
    for (int i = 0; i < lim; ++i) {
        int cur = v[i];
        for (int s = prev + 1; s <= cur; ++s) segstart[s] = c0 + i;
        if (c0 + i == total - 1)
            for (int s = cur + 1; s <= n_seg_pad; ++s) segstart[s] = total;
        prev = cur;
    }
}

__global__ void reduce_partials(const float* __restrict__ p, int n,
                                float* __restrict__ out, float base) {
    __shared__ float red[16];
    float acc = 0.f;
    int nt4 = n >> 2;
    const float4* p4 = (const float4*)p;
    for (int i = threadIdx.x; i < nt4; i += 1024) { float4 v = p4[i]; acc += v.x + v.y + v.z + v.w; }
    for (int i = (nt4 << 2) + threadIdx.x; i < n; i += 1024) acc += p[i];
    #pragma unroll
    for (int off = 32; off > 0; off >>= 1) acc += __shfl_down(acc, off, 64);
    int wid = threadIdx.x >> 6, lane = threadIdx.x & 63;
    if (lane == 0) red[wid] = acc;
    __syncthreads();
    if (threadIdx.x == 0) { float s = base; for (int i = 0; i < 16; ++i) s += red[i]; out[0] = s; }
}

__global__ void init_out(float* out, float v) {
    if (threadIdx.x == 0 && blockIdx.x == 0) out[0] = v;
}

__device__ __forceinline__ int lower_bound64(const int* __restrict__ seg,
                                             int lo, int hi, int target, int lane) {
    while (hi - lo > 64) {
        int step = (hi - lo) >> 6;
        int idx = lo + lane * step;
        int v = seg[idx];
        unsigned long long mask = __ballot(v < target);
        if (mask == 0ull) { hi = lo; break; }
        int k = 63 - __clzll(mask);
        int nhi = (k == 63) ? hi : (lo + (k + 1) * step);
        lo = lo + k * step; hi = nhi;
    }
    if (hi > lo) {
        int idx = lo + lane;
        int v = (idx < hi) ? seg[idx] : 0x7FFFFFFF;
        lo += __popcll(__ballot(v < target));
    }
    return lo;
}

// ---------------- persistent pipelined main kernel ----------------
#define DECL_STATE(S) \
    int hid_##S[4], rid_##S[4], cbg_##S = 0, ce_##S = 0, wb_##S = 0; \
    bool val_##S = false; u8s sl0_##S; u4s sl1_##S; float hv_##S[16];

#define ISSUE_A(S, c) do { \
    val_##S = (c) < nchunks; \
    if (val_##S) { \
        int s0_ = (c) * SPW; \
        cbg_##S = segstart[s0_]; ce_##S = segstart[s0_ + SPW]; \
        wb_##S = cbg_##S & ~7; \
        _Pragma("unroll") \
        for (int j_ = 0; j_ < 4; ++j_) { \
            int s_ = s0_ + g4 * 4 + j_; bool v_ = s_ < n_triples; \
            hid_##S[j_] = v_ ? head_ids[s_] : 0; \
            rid_##S[j_] = v_ ? rel_ids[s_] : 0; } \
        sl0_##S = *(const u8s*)&packed[min(wb_##S + lane * 8, total_chars - 8)]; \
        sl1_##S = *(const u4s*)&packed[min(wb_##S + 512 + lane * 4, total_chars - 4)]; \
    } } while (0)

#define ISSUE_B(S) do { if (val_##S) { \
    _Pragma("unroll") \
    for (int r_ = 0; r_ < 4; ++r_) \
        _Pragma("unroll") \
        for (int ct_ = 0; ct_ < 4; ++ct_) \
            hv_##S[r_ * 4 + ct_] = ent_emb[(size_t)hid_##S[r_] * D + ct_ * 16 + col]; \
    } } while (0)

#define COMPUTE(S, T, c) do { if (val_##S) { \
    _Pragma("unroll") \
    for (int i_ = 0; i_ < 9; ++i_) { \
        int idx_ = i_ * 64 + lane; \
        if (idx_ < HWORDS / 4) ((uint4*)hq)[idx_] = make_uint4(0u,0u,0u,0u); } \
    _Pragma("unroll") \
    for (int e_ = 0; e_ < 8; ++e_) { \
        int c_ = wb_##S + lane * 8 + e_; \
        if (c_ >= cbg_##S && c_ < ce_##S) atomicAdd(&hq[sl0_##S[e_]], 1u); } \
    _Pragma("unroll") \
    for (int e_ = 0; e_ < 4; ++e_) { \
        int c_ = wb_##S + 512 + lane * 4 + e_; \
        if (c_ >= cbg_##S && c_ < ce_##S) atomicAdd(&hq[sl1_##S[e_]], 1u); } \
    for (int c_ = wb_##S + 768 + lane; c_ < ce_##S; c_ += 64) \
        atomicAdd(&hq[packed[c_]], 1u); \
    ISSUE_B(T); \
    f4v acc[4] = {(f4v)0.f, (f4v)0.f, (f4v)0.f, (f4v)0.f}; \
    _Pragma("unroll") \
    for (int st_ = 0; st_ < 4; ++st_) { \
        const unsigned* hr_ = &hq[col * HPW + st_ * 32 + g4 * 8]; \
        uint4 c0_ = *(const uint4*)hr_; \
        uint4 c1_ = *(const uint4*)(hr_ + 4); \
        int4 aw_; \
        aw_.x = pack2(c0_.x, c0_.y); aw_.y = pack2(c0_.z, c0_.w); \
        aw_.z = pack2(c1_.x, c1_.y); aw_.w = pack2(c1_.z, c1_.w); \
        s8v af_ = __builtin_bit_cast(s8v, aw_); \
        _Pragma("unroll") \
        for (int ct_ = 0; ct_ < 4; ++ct_) { \
            s8v bf_ = *(const s8v*)&tabT[(size_t)(ct_ * 16 + col) * CHARSET + st_ * 32 + g4 * 8]; \
            acc[ct_] = __builtin_amdgcn_mfma_f32_16x16x32_bf16(af_, bf_, acc[ct_], 0, 0, 0); } } \
    _Pragma("unroll") \
    for (int r_ = 0; r_ < 4; ++r_) { \
        int s_ = (c) * SPW + g4 * 4 + r_; \
        if (s_ < n_triples) { \
            const float* rp_ = &rel_emb[rid_##S[r_] * D]; \
            _Pragma("unroll") \
            for (int ct_ = 0; ct_ < 4; ++ct_) \
                wsum += fabsf(hv_##S[r_ * 4 + ct_] + rp_[ct_ * 16 + col] - acc[ct_][r_]); } } \
    } } while (0)

__global__ __launch_bounds__(64, 2) void attr_persist(
    const int* __restrict__ head_ids,
    const int* __restrict__ rel_ids,
    const float* __restrict__ rel_emb,
    const float* __restrict__ ent_emb,
    const unsigned short* __restrict__ tabT,
    const int* __restrict__ segstart,
    const unsigned short* __restrict__ packed,
    float* __restrict__ partials,
    int n_triples, int total_chars, int nchunks)
{
    __shared__ __align__(16) unsigned hq[HWORDS];     // 8.25 KB

    const int lane = threadIdx.x;
    const int col = lane & 15, g4 = lane >> 4;
    const int NB = gridDim.x;

    DECL_STATE(A); DECL_STATE(B);
    float wsum = 0.f;

    int c = blockIdx.x;
    ISSUE_A(A, c);
    ISSUE_B(A);                       // one-time stall on ids
    while (c < nchunks) {
        ISSUE_A(B, c + NB);
        COMPUTE(A, B, c);             // hides B's load latency
        ISSUE_A(A, c + 2 * NB);
        COMPUTE(B, A, c + NB);        // hides A's load latency
        c += 2 * NB;
    }

    #pragma unroll
    for (int off = 32; off > 0; off >>= 1)
        wsum += __shfl_down(wsum, off, 64);
    if (lane == 0) partials[blockIdx.x] = wsum;
}

// ---------------- fallback (ws too small) ----------------
__global__ __launch_bounds__(64, 4) void attr_fallback(
    const int* __restrict__ char_ids,
    const int* __restrict__ seg_ids,
    const int* __restrict__ head_ids,
    const int* __restrict__ rel_ids,
    const float* __restrict__ char_emb,
    const float* __restrict__ rel_emb,
    const float* __restrict__ ent_emb,
    float* __restrict__ out,
    int n_triples, int total_chars, int nwaves)
{
    __shared__ __align__(16) unsigned hq[HWORDS];
    const int lane  = threadIdx.x;
    const int gwave = blockIdx.x;
    if (gwave >= nwaves) return;
    const int s0  = gwave * SPW;
    const int col = lane & 15, g4 = lane >> 4;

    int hid[4], rid[4];
    #pragma unroll
    for (int j = 0; j < 4; ++j) {
        int s = s0 + g4 * 4 + j;
        bool v = s < n_triples;
        hid[j] = v ? head_ids[s] : 0;
        rid[j] = v ? rel_ids[s]  : 0;
    }
    for (int i = lane; i < HWORDS / 4; i += 64)
        ((uint4*)hq)[i] = make_uint4(0u, 0u, 0u, 0u);
    int cb = lower_bound64(seg_ids, 0, total_chars, s0, lane);
    int ce = lower_bound64(seg_ids, cb, total_chars,
                           min(s0 + SPW, n_triples), lane);
    for (int c = cb + lane; c < ce; c += 64) {
        int sa = seg_ids[c], da = char_ids[c];
        atomicAdd(&hq[(sa - s0) * HPW + da], 1u);
    }
    float hv[16];
    #pragma unroll
    for (int r = 0; r < 4; ++r)
        #pragma unroll
        for (int ct = 0; ct < 4; ++ct)
            hv[r * 4 + ct] = ent_emb[(size_t)hid[r] * D + ct * 16 + col];

    f4v acc[4] = {(f4v)0.f, (f4v)0.f, (f4v)0.f, (f4v)0.f};
    #pragma unroll
    for (int st = 0; st < 4; ++st) {
        const unsigned* hr = &hq[col * HPW + st * 32 + g4 * 8];
        uint4 c0 = *(const uint4*)hr;
        uint4 c1 = *(const uint4*)(hr + 4);
        int4 aw;
        aw.x = pack2(c0.x, c0.y); aw.y = pack2(c0.z, c0.w);
        aw.z = pack2(c1.x, c1.y); aw.w = pack2(c1.z, c1.w);
        s8v af = __builtin_bit_cast(s8v, aw);
        #pragma unroll
        for (int ct = 0; ct < 4; ++ct) {
            s8v bfrag;
            #pragma unroll
            for (int e = 0; e < 8; ++e)
                bfrag[e] = f32_to_bf16(char_emb[(st * 32 + g4 * 8 + e) * D + ct * 16 + col]);
            acc[ct] = __builtin_amdgcn_mfma_f32_16x16x32_bf16(af, bfrag, acc[ct], 0, 0, 0);
        }
    }
    float part = 0.f;
    #pragma unroll
    for (int r = 0; r < 4; ++r) {
        int s = s0 + g4 * 4 + r;
        if (s < n_triples) {
            const float* rp = &rel_emb[rid[r] * D];
            #pragma unroll
            for (int ct = 0; ct < 4; ++ct)
                part += fabsf(hv[r * 4 + ct] + rp[ct * 16 + col] - acc[ct][r]);
        }
    }
    #pragma unroll
    for (int off = 32; off > 0; off >>= 1)
        part += __shfl_down(part, off, 64);
    if (lane == 0) atomicAdd(out, part);
}

extern "C" void kernel_launch(void* const* d_in, const int* in_sizes, int n_in,
                              void* d_out, int out_size, void* d_ws, size_t ws_size,
                              hipStream_t stream) {
    const int*   char_ids = (const int*)  d_in[0];
    const int*   seg_ids  = (const int*)  d_in[1];
    const int*   head_ids = (const int*)  d_in[2];
    const int*   rel_ids  = (const int*)  d_in[3];
    const float* char_emb = (const float*)d_in[4];
    const float* rel_emb  = (const float*)d_in[5];
    const float* ent_emb  = (const float*)d_in[6];
    float* out = (float*)d_out;

    const int total_chars = in_sizes[0];
    const int n_triples   = in_sizes[2];
    const int nchunks   = (n_triples + SPW - 1) / SPW;
    const int n_seg_pad = nchunks * SPW;
    const float base = (float)n_triples * GAMMA;
    const int nblk = min(4096, nchunks);

    // ws: tabT bf16[8192] | segstart int[n_seg_pad+1] | partials float[nblk]
    //     | packed ushort[total_chars] (16B-aligned)
    unsigned short* tabT = (unsigned short*)d_ws;
    int*   segstart = (int*)((char*)d_ws + D * CHARSET * sizeof(unsigned short));
    float* partials = (float*)(segstart + n_seg_pad + 1);
    size_t off = ((size_t)((char*)(partials + nblk) - (char*)d_ws) + 15) & ~(size_t)15;
    unsigned short* packed = (unsigned short*)((char*)d_ws + off);
    const size_t need = off + (size_t)total_chars * sizeof(unsigned short);

    if (ws_size >= need) {
        const int pthreads = (total_chars + 3) / 4;
        preproc<<<(pthreads + 255) / 256, 256, 0, stream>>>(
            seg_ids, char_ids, char_emb, total_chars, n_seg_pad,
            segstart, packed, tabT);
        attr_persist<<<nblk, 64, 0, stream>>>(
            head_ids, rel_ids, rel_emb, ent_emb, tabT, segstart, packed,
            partials, n_triples, total_chars, nchunks);
        reduce_partials<<<1, 1024, 0, stream>>>(partials, nblk, out, base);
    } else {
        init_out<<<1, 64, 0, stream>>>(out, base);
        attr_fallback<<<nchunks, 64, 0, stream>>>(
            char_ids, seg_ids, head_ids, rel_ids,
            char_emb, rel_emb, ent_emb, out,
            n_triples, total_chars, nchunks);
    }
}

// Round 18
// 30.707 us; speedup vs baseline: 1.7235x; 1.2218x over previous
//
#include <hip/hip_runtime.h>

#define D 64
#define CHARSET 128
#define GAMMA 1.0f
#define SPW 16          // segments per chunk
#define HPW 132         // padded hist row length (u32 words)
#define HWORDS (SPW * HPW)
#define NREL 22

typedef short  s8v  __attribute__((ext_vector_type(8)));   // bf16x8 (4 VGPR)
typedef float  f4v  __attribute__((ext_vector_type(4)));   // fp32x4 accum
typedef unsigned short u8s __attribute__((ext_vector_type(8)));
typedef unsigned short u4s __attribute__((ext_vector_type(4)));

__device__ __forceinline__ short f32_to_bf16(float f) {
    unsigned u = __builtin_bit_cast(unsigned, f);
    unsigned r = (u + 0x7FFFu + ((u >> 16) & 1u)) >> 16;   // RNE
    return (short)r;
}

// pack bf16(a)|bf16(b)<<16 for small ints (exact for ints < 256)
__device__ __forceinline__ int pack2(unsigned ca, unsigned cb) {
    unsigned fa = __builtin_bit_cast(unsigned, (float)ca);
    unsigned fb = __builtin_bit_cast(unsigned, (float)cb);
    return (int)__builtin_amdgcn_perm(fb, fa, 0x07060302u);
}

// Fused preproc: packed[c] = (seg[c]&15)*132 + char[c], segstart, bf16 tabT.
__global__ void preproc(const int* __restrict__ seg, const int* __restrict__ chr,
                        const float* __restrict__ emb,
                        int total, int n_seg_pad,
                        int* __restrict__ segstart,
                        unsigned short* __restrict__ packed,
                        unsigned short* __restrict__ tabT) {
    int q = blockIdx.x * blockDim.x + threadIdx.x;
    if (q < D * CHARSET) {
        int d = q >> 7, k = q & 127;
        tabT[q] = (unsigned short)f32_to_bf16(emb[k * D + d]);
    }
    int c0 = q * 4;
    if (c0 >= total) return;
    int v[4], ch[4];
    if (c0 + 3 < total) {
        int4 w = *(const int4*)&seg[c0]; v[0]=w.x; v[1]=w.y; v[2]=w.z; v[3]=w.w;
        int4 x = *(const int4*)&chr[c0]; ch[0]=x.x; ch[1]=x.y; ch[2]=x.z; ch[3]=x.w;
    } else {
        for (int i = 0; i < 4; ++i) {
            v[i]  = (c0 + i < total) ? seg[c0 + i] : 0;
            ch[i] = (c0 + i < total) ? chr[c0 + i] : 0;
        }
    }
    u4s pk;
    #pragma unroll
    for (int i = 0; i < 4; ++i)
        pk[i] = (unsigned short)((v[i] & (SPW - 1)) * HPW + ch[i]);
    if (c0 + 3 < total) *(u4s*)&packed[c0] = pk;
    else for (int i = 0; i < 4 && c0 + i < total; ++i) packed[c0 + i] = pk[i];

    int prev = (c0 == 0) ? -1 : seg[c0 - 1];
    int lim = min(4, total - c0);
    for (int i = 0; i < lim; ++i) {
        int cur = v[i];
        for (int s = prev + 1; s <= cur; ++s) segstart[s] = c0 + i;
        if (c0 + i == total - 1)
            for (int s = cur + 1; s <= n_seg_pad; ++s) segstart[s] = total;
        prev = cur;
    }
}

__global__ void reduce_partials(const float* __restrict__ p, int n,
                                float* __restrict__ out, float base) {
    __shared__ float red[16];
    float acc = 0.f;
    for (int i = threadIdx.x; i < n; i += 1024) acc += p[i];
    #pragma unroll
    for (int off = 32; off > 0; off >>= 1) acc += __shfl_down(acc, off, 64);
    int wid = threadIdx.x >> 6, lane = threadIdx.x & 63;
    if (lane == 0) red[wid] = acc;
    __syncthreads();
    if (threadIdx.x == 0) { float s = base; for (int i = 0; i < 16; ++i) s += red[i]; out[0] = s; }
}

__global__ void init_out(float* out, float v) {
    if (threadIdx.x == 0 && blockIdx.x == 0) out[0] = v;
}

__device__ __forceinline__ int lower_bound64(const int* __restrict__ seg,
                                             int lo, int hi, int target, int lane) {
    while (hi - lo > 64) {
        int step = (hi - lo) >> 6;
        int idx = lo + lane * step;
        int v = seg[idx];
        unsigned long long mask = __ballot(v < target);
        if (mask == 0ull) { hi = lo; break; }
        int k = 63 - __clzll(mask);
        int nhi = (k == 63) ? hi : (lo + (k + 1) * step);
        lo = lo + k * step; hi = nhi;
    }
    if (hi > lo) {
        int idx = lo + lane;
        int v = (idx < hi) ? seg[idx] : 0x7FFFFFFF;
        lo += __popcll(__ballot(v < target));
    }
    return lo;
}

// ---------------- persistent pipelined main kernel (R15 config) ----------------
#define DECL_STATE(S) \
    int hid_##S[4], rid_##S[4], cbg_##S = 0, ce_##S = 0, wb_##S = 0; \
    bool val_##S = false; u8s sl0_##S; u4s sl1_##S; float hv_##S[16];

#define ISSUE_A(S, c) do { \
    val_##S = (c) < nchunks; \
    if (val_##S) { \
        int s0_ = (c) * SPW; \
        cbg_##S = segstart[s0_]; ce_##S = segstart[s0_ + SPW]; \
        wb_##S = cbg_##S & ~7; \
        _Pragma("unroll") \
        for (int j_ = 0; j_ < 4; ++j_) { \
            int s_ = s0_ + g4 * 4 + j_; bool v_ = s_ < n_triples; \
            hid_##S[j_] = v_ ? head_ids[s_] : 0; \
            rid_##S[j_] = v_ ? rel_ids[s_] : 0; } \
        sl0_##S = *(const u8s*)&packed[min(wb_##S + lane * 8, total_chars - 8)]; \
        sl1_##S = *(const u4s*)&packed[min(wb_##S + 512 + lane * 4, total_chars - 4)]; \
    } } while (0)

#define ISSUE_B(S) do { if (val_##S) { \
    _Pragma("unroll") \
    for (int r_ = 0; r_ < 4; ++r_) \
        _Pragma("unroll") \
        for (int ct_ = 0; ct_ < 4; ++ct_) \
            hv_##S[r_ * 4 + ct_] = ent_emb[(size_t)hid_##S[r_] * D + ct_ * 16 + col]; \
    } } while (0)

#define COMPUTE(S, T, c) do { if (val_##S) { \
    _Pragma("unroll") \
    for (int i_ = 0; i_ < 9; ++i_) { \
        int idx_ = i_ * 64 + lane; \
        if (idx_ < HWORDS / 4) ((uint4*)hq)[idx_] = make_uint4(0u,0u,0u,0u); } \
    _Pragma("unroll") \
    for (int e_ = 0; e_ < 8; ++e_) { \
        int c_ = wb_##S + lane * 8 + e_; \
        if (c_ >= cbg_##S && c_ < ce_##S) atomicAdd(&hq[sl0_##S[e_]], 1u); } \
    _Pragma("unroll") \
    for (int e_ = 0; e_ < 4; ++e_) { \
        int c_ = wb_##S + 512 + lane * 4 + e_; \
        if (c_ >= cbg_##S && c_ < ce_##S) atomicAdd(&hq[sl1_##S[e_]], 1u); } \
    for (int c_ = wb_##S + 768 + lane; c_ < ce_##S; c_ += 64) \
        atomicAdd(&hq[packed[c_]], 1u); \
    ISSUE_B(T); \
    f4v acc[4] = {(f4v)0.f, (f4v)0.f, (f4v)0.f, (f4v)0.f}; \
    _Pragma("unroll") \
    for (int st_ = 0; st_ < 4; ++st_) { \
        const unsigned* hr_ = &hq[col * HPW + st_ * 32 + g4 * 8]; \
        uint4 c0_ = *(const uint4*)hr_; \
        uint4 c1_ = *(const uint4*)(hr_ + 4); \
        int4 aw_; \
        aw_.x = pack2(c0_.x, c0_.y); aw_.y = pack2(c0_.z, c0_.w); \
        aw_.z = pack2(c1_.x, c1_.y); aw_.w = pack2(c1_.z, c1_.w); \
        s8v af_ = __builtin_bit_cast(s8v, aw_); \
        _Pragma("unroll") \
        for (int ct_ = 0; ct_ < 4; ++ct_) \
            acc[ct_] = __builtin_amdgcn_mfma_f32_16x16x32_bf16(af_, bf[st_][ct_], acc[ct_], 0, 0, 0); } \
    _Pragma("unroll") \
    for (int r_ = 0; r_ < 4; ++r_) { \
        int s_ = (c) * SPW + g4 * 4 + r_; \
        if (s_ < n_triples) { \
            const float* rp_ = &lrel[rid_##S[r_] * D]; \
            _Pragma("unroll") \
            for (int ct_ = 0; ct_ < 4; ++ct_) \
                wsum += fabsf(hv_##S[r_ * 4 + ct_] + rp_[ct_ * 16 + col] - acc[ct_][r_]); } } \
    } } while (0)

__global__ __launch_bounds__(64, 2) void attr_persist(
    const int* __restrict__ head_ids,
    const int* __restrict__ rel_ids,
    const float* __restrict__ rel_emb,
    const float* __restrict__ ent_emb,
    const unsigned short* __restrict__ tabT,
    const int* __restrict__ segstart,
    const unsigned short* __restrict__ packed,
    float* __restrict__ partials,
    int n_triples, int total_chars, int nchunks)
{
    __shared__ __align__(16) unsigned hq[HWORDS];     // 8.25 KB
    __shared__ __align__(16) float lrel[NREL * D];    // 5.5 KB

    const int lane = threadIdx.x;
    const int col = lane & 15, g4 = lane >> 4;
    const int NB = gridDim.x;

    // stage rel table (no barrier needed: single-wave block)
    for (int i = lane; i < NREL * D / 4; i += 64)
        ((float4*)lrel)[i] = ((const float4*)rel_emb)[i];

    // hoist B fragments once per wave (64 VGPRs)
    s8v bf[4][4];
    #pragma unroll
    for (int st = 0; st < 4; ++st)
        #pragma unroll
        for (int ct = 0; ct < 4; ++ct)
            bf[st][ct] = *(const s8v*)&tabT[(size_t)(ct * 16 + col) * CHARSET + st * 32 + g4 * 8];

    DECL_STATE(A); DECL_STATE(B);
    float wsum = 0.f;

    int c = blockIdx.x;
    ISSUE_A(A, c);
    ISSUE_B(A);                       // one-time stall on ids
    while (c < nchunks) {
        ISSUE_A(B, c + NB);
        COMPUTE(A, B, c);             // hides B's load latency
        ISSUE_A(A, c + 2 * NB);
        COMPUTE(B, A, c + NB);        // hides A's load latency
        c += 2 * NB;
    }

    #pragma unroll
    for (int off = 32; off > 0; off >>= 1)
        wsum += __shfl_down(wsum, off, 64);
    if (lane == 0) partials[blockIdx.x] = wsum;
}

// ---------------- fallback (ws too small) ----------------
__global__ __launch_bounds__(64, 4) void attr_fallback(
    const int* __restrict__ char_ids,
    const int* __restrict__ seg_ids,
    const int* __restrict__ head_ids,
    const int* __restrict__ rel_ids,
    const float* __restrict__ char_emb,
    const float* __restrict__ rel_emb,
    const float* __restrict__ ent_emb,
    float* __restrict__ out,
    int n_triples, int total_chars, int nwaves)
{
    __shared__ __align__(16) unsigned hq[HWORDS];
    const int lane  = threadIdx.x;
    const int gwave = blockIdx.x;
    if (gwave >= nwaves) return;
    const int s0  = gwave * SPW;
    const int col = lane & 15, g4 = lane >> 4;

    int hid[4], rid[4];
    #pragma unroll
    for (int j = 0; j < 4; ++j) {
        int s = s0 + g4 * 4 + j;
        bool v = s < n_triples;
        hid[j] = v ? head_ids[s] : 0;
        rid[j] = v ? rel_ids[s]  : 0;
    }
    for (int i = lane; i < HWORDS / 4; i += 64)
        ((uint4*)hq)[i] = make_uint4(0u, 0u, 0u, 0u);
    int cb = lower_bound64(seg_ids, 0, total_chars, s0, lane);
    int ce = lower_bound64(seg_ids, cb, total_chars,
                           min(s0 + SPW, n_triples), lane);
    for (int c = cb + lane; c < ce; c += 64) {
        int sa = seg_ids[c], da = char_ids[c];
        atomicAdd(&hq[(sa - s0) * HPW + da], 1u);
    }
    float hv[16];
    #pragma unroll
    for (int r = 0; r < 4; ++r)
        #pragma unroll
        for (int ct = 0; ct < 4; ++ct)
            hv[r * 4 + ct] = ent_emb[(size_t)hid[r] * D + ct * 16 + col];

    f4v acc[4] = {(f4v)0.f, (f4v)0.f, (f4v)0.f, (f4v)0.f};
    #pragma unroll
    for (int st = 0; st < 4; ++st) {
        const unsigned* hr = &hq[col * HPW + st * 32 + g4 * 8];
        uint4 c0 = *(const uint4*)hr;
        uint4 c1 = *(const uint4*)(hr + 4);
        int4 aw;
        aw.x = pack2(c0.x, c0.y); aw.y = pack2(c0.z, c0.w);
        aw.z = pack2(c1.x, c1.y); aw.w = pack2(c1.z, c1.w);
        s8v af = __builtin_bit_cast(s8v, aw);
        #pragma unroll
        for (int ct = 0; ct < 4; ++ct) {
            s8v bfrag;
            #pragma unroll
            for (int e = 0; e < 8; ++e)
                bfrag[e] = f32_to_bf16(char_emb[(st * 32 + g4 * 8 + e) * D + ct * 16 + col]);
            acc[ct] = __builtin_amdgcn_mfma_f32_16x16x32_bf16(af, bfrag, acc[ct], 0, 0, 0);
        }
    }
    float part = 0.f;
    #pragma unroll
    for (int r = 0; r < 4; ++r) {
        int s = s0 + g4 * 4 + r;
        if (s < n_triples) {
            const float* rp = &rel_emb[rid[r] * D];
            #pragma unroll
            for (int ct = 0; ct < 4; ++ct)
                part += fabsf(hv[r * 4 + ct] + rp[ct * 16 + col] - acc[ct][r]);
        }
    }
    #pragma unroll
    for (int off = 32; off > 0; off >>= 1)
        part += __shfl_down(part, off, 64);
    if (lane == 0) atomicAdd(out, part);
}

extern "C" void kernel_launch(void* const* d_in, const int* in_sizes, int n_in,
                              void* d_out, int out_size, void* d_ws, size_t ws_size,
                              hipStream_t stream) {
    const int*   char_ids = (const int*)  d_in[0];
    const int*   seg_ids  = (const int*)  d_in[1];
    const int*   head_ids = (const int*)  d_in[2];
    const int*   rel_ids  = (const int*)  d_in[3];
    const float* char_emb = (const float*)d_in[4];
    const float* rel_emb  = (const float*)d_in[5];
    const float* ent_emb  = (const float*)d_in[6];
    float* out = (float*)d_out;

    const int total_chars = in_sizes[0];
    const int n_triples   = in_sizes[2];
    const int nchunks   = (n_triples + SPW - 1) / SPW;
    const int n_seg_pad = nchunks * SPW;
    const float base = (float)n_triples * GAMMA;
    const int nblk = min(2048, nchunks);

    // ws: tabT bf16[8192] | segstart int[n_seg_pad+1] | partials float[nblk]
    //     | packed ushort[total_chars] (16B-aligned)
    unsigned short* tabT = (unsigned short*)d_ws;
    int*   segstart = (int*)((char*)d_ws + D * CHARSET * sizeof(unsigned short));
    float* partials = (float*)(segstart + n_seg_pad + 1);
    size_t off = ((size_t)((char*)(partials + nblk) - (char*)d_ws) + 15) & ~(size_t)15;
    unsigned short* packed = (unsigned short*)((char*)d_ws + off);
    const size_t need = off + (size_t)total_chars * sizeof(unsigned short);

    if (ws_size >= need) {
        const int pthreads = (total_chars + 3) / 4;
        preproc<<<(pthreads + 255) / 256, 256, 0, stream>>>(
            seg_ids, char_ids, char_emb, total_chars, n_seg_pad,
            segstart, packed, tabT);
        attr_persist<<<nblk, 64, 0, stream>>>(
            head_ids, rel_ids, rel_emb, ent_emb, tabT, segstart, packed,
            partials, n_triples, total_chars, nchunks);
        reduce_partials<<<1, 1024, 0, stream>>>(partials, nblk, out, base);
    } else {
        init_out<<<1, 64, 0, stream>>>(out, base);
        attr_fallback<<<nchunks, 64, 0, stream>>>(
            char_ids, seg_ids, head_ids, rel_ids,
            char_emb, rel_emb, ent_emb, out,
            n_triples, total_chars, nchunks);
    }
}

// Round 20
// 30.170 us; speedup vs baseline: 1.7542x; 1.0178x over previous
//
#include <hip/hip_runtime.h>

#define D 64
#define CHARSET 128
#define GAMMA 1.0f
#define SPW 16          // segments per chunk
#define HPW 132         // padded hist row length (u32 words)
#define HWORDS (SPW * HPW)
#define NREL 22

typedef short  s8v  __attribute__((ext_vector_type(8)));   // bf16x8 (4 VGPR)
typedef float  f4v  __attribute__((ext_vector_type(4)));   // fp32x4 accum
typedef unsigned short u8s __attribute__((ext_vector_type(8)));
typedef unsigned short u4s __attribute__((ext_vector_type(4)));

__device__ __forceinline__ short f32_to_bf16(float f) {
    unsigned u = __builtin_bit_cast(unsigned, f);
    unsigned r = (u + 0x7FFFu + ((u >> 16) & 1u)) >> 16;   // RNE
    return (short)r;
}

// pack bf16(a)|bf16(b)<<16 for small ints (exact for ints < 256)
__device__ __forceinline__ int pack2(unsigned ca, unsigned cb) {
    unsigned fa = __builtin_bit_cast(unsigned, (float)ca);
    unsigned fb = __builtin_bit_cast(unsigned, (float)cb);
    return (int)__builtin_amdgcn_perm(fb, fa, 0x07060302u);
}

// Fused preproc: packed[c] = (seg[c]&15)*132 + char[c], segstart, bf16 tabT.
__global__ void preproc(const int* __restrict__ seg, const int* __restrict__ chr,
                        const float* __restrict__ emb,
                        int total, int n_seg_pad,
                        int* __restrict__ segstart,
                        unsigned short* __restrict__ packed,
                        unsigned short* __restrict__ tabT) {
    int q = blockIdx.x * blockDim.x + threadIdx.x;
    if (q < D * CHARSET) {
        int d = q >> 7, k = q & 127;
        tabT[q] = (unsigned short)f32_to_bf16(emb[k * D + d]);
    }
    int c0 = q * 4;
    if (c0 >= total) return;
    int v[4], ch[4];
    if (c0 + 3 < total) {
        int4 w = *(const int4*)&seg[c0]; v[0]=w.x; v[1]=w.y; v[2]=w.z; v[3]=w.w;
        int4 x = *(const int4*)&chr[c0]; ch[0]=x.x; ch[1]=x.y; ch[2]=x.z; ch[3]=x.w;
    } else {
        for (int i = 0; i < 4; ++i) {
            v[i]  = (c0 + i < total) ? seg[c0 + i] : 0;
            ch[i] = (c0 + i < total) ? chr[c0 + i] : 0;
        }
    }
    u4s pk;
    #pragma unroll
    for (int i = 0; i < 4; ++i)
        pk[i] = (unsigned short)((v[i] & (SPW - 1)) * HPW + ch[i]);
    if (c0 + 3 < total) *(u4s*)&packed[c0] = pk;
    else for (int i = 0; i < 4 && c0 + i < total; ++i) packed[c0 + i] = pk[i];

    int prev = (c0 == 0) ? -1 : seg[c0 - 1];
    int lim = min(4, total - c0);
    for (int i = 0; i < lim; ++i) {
        int cur = v[i];
        for (int s = prev + 1; s <= cur; ++s) segstart[s] = c0 + i;
        if (c0 + i == total - 1)
            for (int s = cur + 1; s <= n_seg_pad; ++s) segstart[s] = total;
        prev = cur;
    }
}

__global__ void reduce_partials(const float* __restrict__ p, int n,
                                float* __restrict__ out, float base) {
    __shared__ float red[16];
    float acc = 0.f;
    for (int i = threadIdx.x; i < n; i += 1024) acc += p[i];
    #pragma unroll
    for (int off = 32; off > 0; off >>= 1) acc += __shfl_down(acc, off, 64);
    int wid = threadIdx.x >> 6, lane = threadIdx.x & 63;
    if (lane == 0) red[wid] = acc;
    __syncthreads();
    if (threadIdx.x == 0) { float s = base; for (int i = 0; i < 16; ++i) s += red[i]; out[0] = s; }
}

__global__ void init_out(float* out, float v) {
    if (threadIdx.x == 0 && blockIdx.x == 0) out[0] = v;
}

__device__ __forceinline__ int lower_bound64(const int* __restrict__ seg,
                                             int lo, int hi, int target, int lane) {
    while (hi - lo > 64) {
        int step = (hi - lo) >> 6;
        int idx = lo + lane * step;
        int v = seg[idx];
        unsigned long long mask = __ballot(v < target);
        if (mask == 0ull) { hi = lo; break; }
        int k = 63 - __clzll(mask);
        int nhi = (k == 63) ? hi : (lo + (k + 1) * step);
        lo = lo + k * step; hi = nhi;
    }
    if (hi > lo) {
        int idx = lo + lane;
        int v = (idx < hi) ? seg[idx] : 0x7FFFFFFF;
        lo += __popcll(__ballot(v < target));
    }
    return lo;
}

// ---------------- persistent 3-stage pipelined main kernel ----------------
// Stage 1: LOAD_BND  (wave-uniform segstart pair -> SGPRs), one phase early
// Stage 2: ISSUE_DATA (ids + packed loads; boundaries already resident)
// Stage 3: COMPUTE    (zero/atomics/MFMA/epilogue; issues next hv gathers)
#define DECL_STATE(S) \
    int hid_##S[4], rid_##S[4], cbg_##S = 0, cend_##S = 0, wb_##S = 0; \
    bool val_##S = false; u8s sl0_##S; u4s sl1_##S; float hv_##S[16];

#define LOAD_BND(bb_, ee_, c) do { \
    if ((c) < nchunks) { bb_ = segstart[(c) * SPW]; ee_ = segstart[(c) * SPW + SPW]; } \
    else { bb_ = 0; ee_ = 0; } } while (0)

#define ISSUE_DATA(S, c, bb_, ee_) do { \
    val_##S = (c) < nchunks; \
    if (val_##S) { \
        int s0_ = (c) * SPW; \
        cbg_##S = bb_; cend_##S = ee_; wb_##S = bb_ & ~7; \
        _Pragma("unroll") \
        for (int j_ = 0; j_ < 4; ++j_) { \
            int s_ = s0_ + g4 * 4 + j_; bool v_ = s_ < n_triples; \
            hid_##S[j_] = v_ ? head_ids[s_] : 0; \
            rid_##S[j_] = v_ ? rel_ids[s_] : 0; } \
        sl0_##S = *(const u8s*)&packed[min(wb_##S + lane * 8, total_chars - 8)]; \
        sl1_##S = *(const u4s*)&packed[min(wb_##S + 512 + lane * 4, total_chars - 4)]; \
    } } while (0)

#define ISSUE_B(S) do { if (val_##S) { \
    _Pragma("unroll") \
    for (int r_ = 0; r_ < 4; ++r_) \
        _Pragma("unroll") \
        for (int ct_ = 0; ct_ < 4; ++ct_) \
            hv_##S[r_ * 4 + ct_] = ent_emb[(size_t)hid_##S[r_] * D + ct_ * 16 + col]; \
    } } while (0)

#define COMPUTE(S, T, c) do { if (val_##S) { \
    _Pragma("unroll") \
    for (int i_ = 0; i_ < 9; ++i_) { \
        int idx_ = i_ * 64 + lane; \
        if (idx_ < HWORDS / 4) ((uint4*)hq)[idx_] = make_uint4(0u,0u,0u,0u); } \
    _Pragma("unroll") \
    for (int e_ = 0; e_ < 8; ++e_) { \
        int c_ = wb_##S + lane * 8 + e_; \
        if (c_ >= cbg_##S && c_ < cend_##S) atomicAdd(&hq[sl0_##S[e_]], 1u); } \
    _Pragma("unroll") \
    for (int e_ = 0; e_ < 4; ++e_) { \
        int c_ = wb_##S + 512 + lane * 4 + e_; \
        if (c_ >= cbg_##S && c_ < cend_##S) atomicAdd(&hq[sl1_##S[e_]], 1u); } \
    for (int c_ = wb_##S + 768 + lane; c_ < cend_##S; c_ += 64) \
        atomicAdd(&hq[packed[c_]], 1u); \
    ISSUE_B(T); \
    f4v acc[4] = {(f4v)0.f, (f4v)0.f, (f4v)0.f, (f4v)0.f}; \
    _Pragma("unroll") \
    for (int st_ = 0; st_ < 4; ++st_) { \
        const unsigned* hr_ = &hq[col * HPW + st_ * 32 + g4 * 8]; \
        uint4 c0_ = *(const uint4*)hr_; \
        uint4 c1_ = *(const uint4*)(hr_ + 4); \
        int4 aw_; \
        aw_.x = pack2(c0_.x, c0_.y); aw_.y = pack2(c0_.z, c0_.w); \
        aw_.z = pack2(c1_.x, c1_.y); aw_.w = pack2(c1_.z, c1_.w); \
        s8v af_ = __builtin_bit_cast(s8v, aw_); \
        _Pragma("unroll") \
        for (int ct_ = 0; ct_ < 4; ++ct_) \
            acc[ct_] = __builtin_amdgcn_mfma_f32_16x16x32_bf16(af_, bf[st_][ct_], acc[ct_], 0, 0, 0); } \
    _Pragma("unroll") \
    for (int r_ = 0; r_ < 4; ++r_) { \
        int s_ = (c) * SPW + g4 * 4 + r_; \
        if (s_ < n_triples) { \
            const float* rp_ = &lrel[rid_##S[r_] * D]; \
            _Pragma("unroll") \
            for (int ct_ = 0; ct_ < 4; ++ct_) \
                wsum += fabsf(hv_##S[r_ * 4 + ct_] + rp_[ct_ * 16 + col] - acc[ct_][r_]); } } \
    } } while (0)

__global__ __launch_bounds__(64, 2) void attr_persist(
    const int* __restrict__ head_ids,
    const int* __restrict__ rel_ids,
    const float* __restrict__ rel_emb,
    const float* __restrict__ ent_emb,
    const unsigned short* __restrict__ tabT,
    const int* __restrict__ segstart,
    const unsigned short* __restrict__ packed,
    float* __restrict__ partials,
    int n_triples, int total_chars, int nchunks)
{
    __shared__ __align__(16) unsigned hq[HWORDS];     // 8.25 KB
    __shared__ __align__(16) float lrel[NREL * D];    // 5.5 KB

    const int lane = threadIdx.x;
    const int col = lane & 15, g4 = lane >> 4;
    const int NB = gridDim.x;

    // stage rel table (no barrier needed: single-wave block)
    for (int i = lane; i < NREL * D / 4; i += 64)
        ((float4*)lrel)[i] = ((const float4*)rel_emb)[i];

    // hoist B fragments once per wave (64 VGPRs)
    s8v bf[4][4];
    #pragma unroll
    for (int st = 0; st < 4; ++st)
        #pragma unroll
        for (int ct = 0; ct < 4; ++ct)
            bf[st][ct] = *(const s8v*)&tabT[(size_t)(ct * 16 + col) * CHARSET + st * 32 + g4 * 8];

    DECL_STATE(A); DECL_STATE(B);
    float wsum = 0.f;

    int c = blockIdx.x;
    int bndb0 = 0, bnde0 = 0, bndb1 = 0, bnde1 = 0;
    LOAD_BND(bndb0, bnde0, c);            // boundaries for chunk c
    ISSUE_DATA(A, c, bndb0, bnde0);
    ISSUE_B(A);                           // one-time prologue stall
    LOAD_BND(bndb1, bnde1, c + NB);       // boundaries one phase ahead
    while (c < nchunks) {
        LOAD_BND(bndb0, bnde0, c + 2 * NB);       // stage 1 for c+2NB
        ISSUE_DATA(B, c + NB, bndb1, bnde1);      // stage 2 (bnd resident)
        COMPUTE(A, B, c);                         // stage 3 (hides B's loads)
        LOAD_BND(bndb1, bnde1, c + 3 * NB);
        ISSUE_DATA(A, c + 2 * NB, bndb0, bnde0);
        COMPUTE(B, A, c + NB);
        c += 2 * NB;
    }

    #pragma unroll
    for (int off = 32; off > 0; off >>= 1)
        wsum += __shfl_down(wsum, off, 64);
    if (lane == 0) partials[blockIdx.x] = wsum;
}

// ---------------- fallback (ws too small) ----------------
__global__ __launch_bounds__(64, 4) void attr_fallback(
    const int* __restrict__ char_ids,
    const int* __restrict__ seg_ids,
    const int* __restrict__ head_ids,
    const int* __restrict__ rel_ids,
    const float* __restrict__ char_emb,
    const float* __restrict__ rel_emb,
    const float* __restrict__ ent_emb,
    float* __restrict__ out,
    int n_triples, int total_chars, int nwaves)
{
    __shared__ __align__(16) unsigned hq[HWORDS];
    const int lane  = threadIdx.x;
    const int gwave = blockIdx.x;
    if (gwave >= nwaves) return;
    const int s0  = gwave * SPW;
    const int col = lane & 15, g4 = lane >> 4;

    int hid[4], rid[4];
    #pragma unroll
    for (int j = 0; j < 4; ++j) {
        int s = s0 + g4 * 4 + j;
        bool v = s < n_triples;
        hid[j] = v ? head_ids[s] : 0;
        rid[j] = v ? rel_ids[s]  : 0;
    }
    for (int i = lane; i < HWORDS / 4; i += 64)
        ((uint4*)hq)[i] = make_uint4(0u, 0u, 0u, 0u);
    int cb = lower_bound64(seg_ids, 0, total_chars, s0, lane);
    int ce = lower_bound64(seg_ids, cb, total_chars,
                           min(s0 + SPW, n_triples), lane);
    for (int c = cb + lane; c < ce; c += 64) {
        int sa = seg_ids[c], da = char_ids[c];
        atomicAdd(&hq[(sa - s0) * HPW + da], 1u);
    }
    float hv[16];
    #pragma unroll
    for (int r = 0; r < 4; ++r)
        #pragma unroll
        for (int ct = 0; ct < 4; ++ct)
            hv[r * 4 + ct] = ent_emb[(size_t)hid[r] * D + ct * 16 + col];

    f4v acc[4] = {(f4v)0.f, (f4v)0.f, (f4v)0.f, (f4v)0.f};
    #pragma unroll
    for (int st = 0; st < 4; ++st) {
        const unsigned* hr = &hq[col * HPW + st * 32 + g4 * 8];
        uint4 c0 = *(const uint4*)hr;
        uint4 c1 = *(const uint4*)(hr + 4);
        int4 aw;
        aw.x = pack2(c0.x, c0.y); aw.y = pack2(c0.z, c0.w);
        aw.z = pack2(c1.x, c1.y); aw.w = pack2(c1.z, c1.w);
        s8v af = __builtin_bit_cast(s8v, aw);
        #pragma unroll
        for (int ct = 0; ct < 4; ++ct) {
            s8v bfrag;
            #pragma unroll
            for (int e = 0; e < 8; ++e)
                bfrag[e] = f32_to_bf16(char_emb[(st * 32 + g4 * 8 + e) * D + ct * 16 + col]);
            acc[ct] = __builtin_amdgcn_mfma_f32_16x16x32_bf16(af, bfrag, acc[ct], 0, 0, 0);
        }
    }
    float part = 0.f;
    #pragma unroll
    for (int r = 0; r < 4; ++r) {
        int s = s0 + g4 * 4 + r;
        if (s < n_triples) {
            const float* rp = &rel_emb[rid[r] * D];
            #pragma unroll
            for (int ct = 0; ct < 4; ++ct)
                part += fabsf(hv[r * 4 + ct] + rp[ct * 16 + col] - acc[ct][r]);
        }
    }
    #pragma unroll
    for (int off = 32; off > 0; off >>= 1)
        part += __shfl_down(part, off, 64);
    if (lane == 0) atomicAdd(out, part);
}

extern "C" void kernel_launch(void* const* d_in, const int* in_sizes, int n_in,
                              void* d_out, int out_size, void* d_ws, size_t ws_size,
                              hipStream_t stream) {
    const int*   char_ids = (const int*)  d_in[0];
    const int*   seg_ids  = (const int*)  d_in[1];
    const int*   head_ids = (const int*)  d_in[2];
    const int*   rel_ids  = (const int*)  d_in[3];
    const float* char_emb = (const float*)d_in[4];
    const float* rel_emb  = (const float*)d_in[5];
    const float* ent_emb  = (const float*)d_in[6];
    float* out = (float*)d_out;

    const int total_chars = in_sizes[0];
    const int n_triples   = in_sizes[2];
    const int nchunks   = (n_triples + SPW - 1) / SPW;
    const int n_seg_pad = nchunks * SPW;
    const float base = (float)n_triples * GAMMA;
    const int nblk = min(2048, nchunks);

    // ws: tabT bf16[8192] | segstart int[n_seg_pad+1] | partials float[nblk]
    //     | packed ushort[total_chars] (16B-aligned)
    unsigned short* tabT = (unsigned short*)d_ws;
    int*   segstart = (int*)((char*)d_ws + D * CHARSET * sizeof(unsigned short));
    float* partials = (float*)(segstart + n_seg_pad + 1);
    size_t off = ((size_t)((char*)(partials + nblk) - (char*)d_ws) + 15) & ~(size_t)15;
    unsigned short* packed = (unsigned short*)((char*)d_ws + off);
    const size_t need = off + (size_t)total_chars * sizeof(unsigned short);

    if (ws_size >= need) {
        const int pthreads = (total_chars + 3) / 4;
        preproc<<<(pthreads + 255) / 256, 256, 0, stream>>>(
            seg_ids, char_ids, char_emb, total_chars, n_seg_pad,
            segstart, packed, tabT);
        attr_persist<<<nblk, 64, 0, stream>>>(
            head_ids, rel_ids, rel_emb, ent_emb, tabT, segstart, packed,
            partials, n_triples, total_chars, nchunks);
        reduce_partials<<<1, 1024, 0, stream>>>(partials, nblk, out, base);
    } else {
        init_out<<<1, 64, 0, stream>>>(out, base);
        attr_fallback<<<nchunks, 64, 0, stream>>>(
            char_ids, seg_ids, head_ids, rel_ids,
            char_emb, rel_emb, ent_emb, out,
            n_triples, total_chars, nchunks);
    }
}